// Round 1
// baseline (1120.239 us; speedup 1.0000x reference)
//
#include <hip/hip_runtime.h>
#include <math.h>

#define FEAT 128

// ---------------------------------------------------------------------------
// Kernel 1: w_eff[i][k] = sum_j w[i][j]*clip(d[j],0,1)*w[k][j]
// One block per output row i, 128 threads (k). Stage w transposed in LDS so
// the inner loop is a conflict-free coalesced LDS read.
// ---------------------------------------------------------------------------
__global__ __launch_bounds__(FEAT) void weff_kernel(const float* __restrict__ w,
                                                    const float* __restrict__ d,
                                                    float* __restrict__ weff) {
    __shared__ float wT[FEAT * FEAT];  // wT[j*128+k] = w[k][j]
    __shared__ float as[FEAT];         // a[j] = w[i][j]*clip(d[j])
    const int i = blockIdx.x;
    const int k = threadIdx.x;

    for (int j = 0; j < FEAT; j += 4) {
        float4 v = *reinterpret_cast<const float4*>(&w[k * FEAT + j]);
        wT[(j + 0) * FEAT + k] = v.x;
        wT[(j + 1) * FEAT + k] = v.y;
        wT[(j + 2) * FEAT + k] = v.z;
        wT[(j + 3) * FEAT + k] = v.w;
    }
    float dk = d[k];
    dk = fminf(fmaxf(dk, 0.0f), 1.0f);
    as[k] = w[i * FEAT + k] * dk;
    __syncthreads();

    float acc = 0.0f;
#pragma unroll 8
    for (int j = 0; j < FEAT; ++j)
        acc = fmaf(as[j], wT[j * FEAT + k], acc);
    weff[i * FEAT + k] = acc;
}

// ---------------------------------------------------------------------------
// Kernel 2: build CSR row_ptr from sorted adj_rows. Each entry written once.
// ---------------------------------------------------------------------------
__global__ void rowptr_kernel(const int* __restrict__ rows, int* __restrict__ rp,
                              int E, int N) {
    int e = blockIdx.x * blockDim.x + threadIdx.x;
    if (e >= E) return;
    int r = rows[e];
    int rprev = (e == 0) ? -1 : rows[e - 1];
    for (int rr = rprev + 1; rr <= r; ++rr) rp[rr] = e;
    if (e == E - 1) {
        for (int rr = r + 1; rr <= N; ++rr) rp[rr] = E;
    }
}

// ---------------------------------------------------------------------------
// Kernel 3: fused SpMM + x@w_eff + combine.
// 256 threads = 2 subgroups of 128 (thread owns feature f), 4 rows each.
// ---------------------------------------------------------------------------
__global__ __launch_bounds__(256) void fused_kernel(
    const float* __restrict__ x, const float* __restrict__ x0,
    const float* __restrict__ vals, const float* __restrict__ alpha,
    const int* __restrict__ cols, const int* __restrict__ rp,
    const float* __restrict__ weff, float* __restrict__ out, int N) {
    __shared__ float xs[8 * FEAT];  // 8 staged x rows (4 KB)

    const int rbase = blockIdx.x * 8;
    const int tid = threadIdx.x;
    const int g = tid >> 7;   // subgroup 0/1
    const int f = tid & 127;  // feature

    const int rem = N - rbase;  // rows available in this block (normally >= 8)

    // --- stage the block's 8 x-rows into LDS (contiguous 4 KB) ---
    {
        int idx = tid * 4;
        if (rem >= 8) {
            float4 v = *reinterpret_cast<const float4*>(&x[(size_t)rbase * FEAT + idx]);
            *reinterpret_cast<float4*>(&xs[idx]) = v;
        } else {
            int limit = rem * FEAT;
#pragma unroll
            for (int t = 0; t < 4; ++t) {
                xs[idx + t] = (idx + t < limit) ? x[(size_t)rbase * FEAT + idx + t] : 0.0f;
            }
        }
    }

    // --- SpMM: acc[i] = sum_e vals[e] * x[cols[e]][f] over my 4 rows ---
    float acc[4] = {0.f, 0.f, 0.f, 0.f};
#pragma unroll
    for (int i = 0; i < 4; ++i) {
        int r = rbase + g * 4 + i;
        if (r >= N) break;
        int e = rp[r];
        int e1 = rp[r + 1];
        for (; e + 1 < e1; e += 2) {
            int c0 = cols[e];
            int c1 = cols[e + 1];
            float v0 = vals[e];
            float v1 = vals[e + 1];
            float a0 = x[(size_t)c0 * FEAT + f];
            float a1 = x[(size_t)c1 * FEAT + f];
            acc[i] = fmaf(v0, a0, acc[i]);
            acc[i] = fmaf(v1, a1, acc[i]);
        }
        if (e < e1) {
            acc[i] = fmaf(vals[e], x[(size_t)cols[e] * FEAT + f], acc[i]);
        }
    }
    __syncthreads();

    // --- xw[i] = sum_j xs[row_i][j] * weff[j][f]  (4 rows amortize weff reads) ---
    float xw[4] = {0.f, 0.f, 0.f, 0.f};
    for (int j4 = 0; j4 < FEAT; j4 += 4) {
        float w0 = weff[(j4 + 0) * FEAT + f];
        float w1 = weff[(j4 + 1) * FEAT + f];
        float w2 = weff[(j4 + 2) * FEAT + f];
        float w3 = weff[(j4 + 3) * FEAT + f];
#pragma unroll
        for (int i = 0; i < 4; ++i) {
            float4 xv = *reinterpret_cast<const float4*>(&xs[(g * 4 + i) * FEAT + j4]);
            xw[i] = fmaf(xv.x, w0, xw[i]);
            xw[i] = fmaf(xv.y, w1, xw[i]);
            xw[i] = fmaf(xv.z, w2, xw[i]);
            xw[i] = fmaf(xv.w, w3, xw[i]);
        }
    }

    // --- epilogue: f = sigmoid(alpha)*0.5*(ax - x) + xw - x + x0 ---
#pragma unroll
    for (int i = 0; i < 4; ++i) {
        int r = rbase + g * 4 + i;
        if (r >= N) break;
        float a = alpha[r];
        float al = 1.0f / (1.0f + __expf(-a));
        float xv = xs[(g * 4 + i) * FEAT + f];
        float o = al * 0.5f * (acc[i] - xv) + xw[i] - xv + x0[(size_t)r * FEAT + f];
        out[(size_t)r * FEAT + f] = o;
    }
}

// ---------------------------------------------------------------------------
extern "C" void kernel_launch(void* const* d_in, const int* in_sizes, int n_in,
                              void* d_out, int out_size, void* d_ws, size_t ws_size,
                              hipStream_t stream) {
    const float* x     = (const float*)d_in[0];
    const float* x0    = (const float*)d_in[1];
    const float* vals  = (const float*)d_in[2];
    const float* alpha = (const float*)d_in[3];
    const float* w     = (const float*)d_in[4];
    const float* d     = (const float*)d_in[5];
    const int*   rows  = (const int*)d_in[6];
    const int*   cols  = (const int*)d_in[7];

    const int N = in_sizes[3];  // alpha_train has N elements
    const int E = in_sizes[2];  // adj_vals has E elements

    float* weff = (float*)d_ws;                                   // 64 KiB
    int*   rp   = (int*)((char*)d_ws + FEAT * FEAT * sizeof(float));  // (N+1) ints

    weff_kernel<<<FEAT, FEAT, 0, stream>>>(w, d, weff);
    rowptr_kernel<<<(E + 255) / 256, 256, 0, stream>>>(rows, rp, E, N);

    int nblocks = (N + 7) / 8;
    fused_kernel<<<nblocks, 256, 0, stream>>>(x, x0, vals, alpha, cols, rp, weff,
                                              (float*)d_out, N);
}

// Round 2
// 262.030 us; speedup vs baseline: 4.2752x; 4.2752x over previous
//
#include <hip/hip_runtime.h>
#include <math.h>

#define FEAT 128

// ---------------------------------------------------------------------------
// Kernel 1: w_eff[i][k] = sum_j w[i][j]*clip(d[j],0,1)*w[k][j]
// ---------------------------------------------------------------------------
__global__ __launch_bounds__(FEAT) void weff_kernel(const float* __restrict__ w,
                                                    const float* __restrict__ d,
                                                    float* __restrict__ weff) {
    __shared__ float wT[FEAT * FEAT];  // wT[j*128+k] = w[k][j]
    __shared__ float as[FEAT];         // a[j] = w[i][j]*clip(d[j])
    const int i = blockIdx.x;
    const int k = threadIdx.x;

    for (int j = 0; j < FEAT; j += 4) {
        float4 v = *reinterpret_cast<const float4*>(&w[k * FEAT + j]);
        wT[(j + 0) * FEAT + k] = v.x;
        wT[(j + 1) * FEAT + k] = v.y;
        wT[(j + 2) * FEAT + k] = v.z;
        wT[(j + 3) * FEAT + k] = v.w;
    }
    float dk = d[k];
    dk = fminf(fmaxf(dk, 0.0f), 1.0f);
    as[k] = w[i * FEAT + k] * dk;
    __syncthreads();

    float acc = 0.0f;
#pragma unroll 8
    for (int j = 0; j < FEAT; ++j)
        acc = fmaf(as[j], wT[j * FEAT + k], acc);
    weff[i * FEAT + k] = acc;
}

// ---------------------------------------------------------------------------
// Kernel 2: build CSR row_ptr from sorted adj_rows.
// ---------------------------------------------------------------------------
__global__ void rowptr_kernel(const int* __restrict__ rows, int* __restrict__ rp,
                              int E, int N) {
    int e = blockIdx.x * blockDim.x + threadIdx.x;
    if (e >= E) return;
    int r = rows[e];
    int rprev = (e == 0) ? -1 : rows[e - 1];
    for (int rr = rprev + 1; rr <= r; ++rr) rp[rr] = e;
    if (e == E - 1) {
        for (int rr = r + 1; rr <= N; ++rr) rp[rr] = E;
    }
}

// ---------------------------------------------------------------------------
// Kernel 3: fused SpMM + x@w_eff + combine.
// Phase A: wave-per-row gather. Lane = (sub, fl): sub = edge slot (0/1),
//   fl = feature quad (features fl*4..fl*4+3). One wave-load = 1 KB = 2 edges.
//   Unroll 4 -> 8 edges / 4 KB in flight per wave.
// Phase B: block-cooperative dense xw = x@w_eff (weff reuse) + epilogue.
// ---------------------------------------------------------------------------
__global__ __launch_bounds__(256, 8) void fused_kernel(
    const float* __restrict__ x, const float* __restrict__ x0,
    const float* __restrict__ vals, const float* __restrict__ alpha,
    const int* __restrict__ cols, const int* __restrict__ rp,
    const float* __restrict__ weff, float* __restrict__ out, int N) {
    __shared__ float xs[4][FEAT];   // block's 4 x rows
    __shared__ float axs[4][FEAT];  // block's 4 ax rows

    const int tid = threadIdx.x;
    const int wid = tid >> 6;   // wave 0..3 -> row
    const int lane = tid & 63;
    const int sub = lane >> 5;  // edge slot 0/1
    const int fl = lane & 31;   // feature quad index
    const int rbase = blockIdx.x * 4;
    const int r = rbase + wid;

    // ---------------- Phase A: gather (per-wave, no barrier needed) --------
    if (r < N) {
        // stage x row into LDS (wave-coherent, no barrier needed before own read)
        float2 v = *reinterpret_cast<const float2*>(&x[(size_t)r * FEAT + lane * 2]);
        *reinterpret_cast<float2*>(&xs[wid][lane * 2]) = v;

        const int e0 = rp[r];
        const int e1 = rp[r + 1];
        float4 acc = make_float4(0.f, 0.f, 0.f, 0.f);
        const float* xg = x + fl * 4;

        for (int eb = e0; eb < e1; eb += 8) {
            int ea0 = eb + sub;
            int ea1 = eb + 2 + sub;
            int ea2 = eb + 4 + sub;
            int ea3 = eb + 6 + sub;
            int c0 = -1, c1 = -1, c2 = -1, c3 = -1;
            float v0 = 0.f, v1 = 0.f, v2 = 0.f, v3 = 0.f;
            if (ea0 < e1) { c0 = cols[ea0]; v0 = vals[ea0]; }
            if (ea1 < e1) { c1 = cols[ea1]; v1 = vals[ea1]; }
            if (ea2 < e1) { c2 = cols[ea2]; v2 = vals[ea2]; }
            if (ea3 < e1) { c3 = cols[ea3]; v3 = vals[ea3]; }
            float4 g0 = make_float4(0.f, 0.f, 0.f, 0.f);
            float4 g1 = g0, g2 = g0, g3 = g0;
            if (c0 >= 0) g0 = *reinterpret_cast<const float4*>(&xg[(size_t)c0 * FEAT]);
            if (c1 >= 0) g1 = *reinterpret_cast<const float4*>(&xg[(size_t)c1 * FEAT]);
            if (c2 >= 0) g2 = *reinterpret_cast<const float4*>(&xg[(size_t)c2 * FEAT]);
            if (c3 >= 0) g3 = *reinterpret_cast<const float4*>(&xg[(size_t)c3 * FEAT]);
            acc.x = fmaf(v0, g0.x, acc.x);
            acc.y = fmaf(v0, g0.y, acc.y);
            acc.z = fmaf(v0, g0.z, acc.z);
            acc.w = fmaf(v0, g0.w, acc.w);
            acc.x = fmaf(v1, g1.x, acc.x);
            acc.y = fmaf(v1, g1.y, acc.y);
            acc.z = fmaf(v1, g1.z, acc.z);
            acc.w = fmaf(v1, g1.w, acc.w);
            acc.x = fmaf(v2, g2.x, acc.x);
            acc.y = fmaf(v2, g2.y, acc.y);
            acc.z = fmaf(v2, g2.z, acc.z);
            acc.w = fmaf(v2, g2.w, acc.w);
            acc.x = fmaf(v3, g3.x, acc.x);
            acc.y = fmaf(v3, g3.y, acc.y);
            acc.z = fmaf(v3, g3.z, acc.z);
            acc.w = fmaf(v3, g3.w, acc.w);
        }
        // combine the two edge-slot partials (lane l <-> l+32)
        acc.x += __shfl_xor(acc.x, 32);
        acc.y += __shfl_xor(acc.y, 32);
        acc.z += __shfl_xor(acc.z, 32);
        acc.w += __shfl_xor(acc.w, 32);
        if (sub == 0) {
            *reinterpret_cast<float4*>(&axs[wid][fl * 4]) = acc;
        }
    }
    __syncthreads();

    // ---------------- Phase B: dense xw = x @ weff + epilogue --------------
    const int f = tid & 127;
    const int g = tid >> 7;  // 0/1 -> rows rbase+g*2, rbase+g*2+1
    const float* xs0 = xs[g * 2 + 0];
    const float* xs1 = xs[g * 2 + 1];
    float xw0 = 0.f, xw1 = 0.f;
#pragma unroll 4
    for (int j = 0; j < FEAT; j += 4) {
        float w0 = weff[(j + 0) * FEAT + f];
        float w1 = weff[(j + 1) * FEAT + f];
        float w2 = weff[(j + 2) * FEAT + f];
        float w3 = weff[(j + 3) * FEAT + f];
        xw0 = fmaf(xs0[j + 0], w0, xw0);
        xw0 = fmaf(xs0[j + 1], w1, xw0);
        xw0 = fmaf(xs0[j + 2], w2, xw0);
        xw0 = fmaf(xs0[j + 3], w3, xw0);
        xw1 = fmaf(xs1[j + 0], w0, xw1);
        xw1 = fmaf(xs1[j + 1], w1, xw1);
        xw1 = fmaf(xs1[j + 2], w2, xw1);
        xw1 = fmaf(xs1[j + 3], w3, xw1);
    }

    const int r0 = rbase + g * 2 + 0;
    const int r1 = rbase + g * 2 + 1;
    if (r0 < N) {
        float al = 1.0f / (1.0f + __expf(-alpha[r0]));
        float ax = axs[g * 2 + 0][f];
        float xv = xs0[f];
        out[(size_t)r0 * FEAT + f] =
            al * 0.5f * (ax - xv) + xw0 - xv + x0[(size_t)r0 * FEAT + f];
    }
    if (r1 < N) {
        float al = 1.0f / (1.0f + __expf(-alpha[r1]));
        float ax = axs[g * 2 + 1][f];
        float xv = xs1[f];
        out[(size_t)r1 * FEAT + f] =
            al * 0.5f * (ax - xv) + xw1 - xv + x0[(size_t)r1 * FEAT + f];
    }
}

// ---------------------------------------------------------------------------
extern "C" void kernel_launch(void* const* d_in, const int* in_sizes, int n_in,
                              void* d_out, int out_size, void* d_ws, size_t ws_size,
                              hipStream_t stream) {
    const float* x     = (const float*)d_in[0];
    const float* x0    = (const float*)d_in[1];
    const float* vals  = (const float*)d_in[2];
    const float* alpha = (const float*)d_in[3];
    const float* w     = (const float*)d_in[4];
    const float* d     = (const float*)d_in[5];
    const int*   rows  = (const int*)d_in[6];
    const int*   cols  = (const int*)d_in[7];

    const int N = in_sizes[3];  // alpha_train has N elements
    const int E = in_sizes[2];  // adj_vals has E elements

    float* weff = (float*)d_ws;                                       // 64 KiB
    int*   rp   = (int*)((char*)d_ws + FEAT * FEAT * sizeof(float));  // (N+1) ints

    weff_kernel<<<FEAT, FEAT, 0, stream>>>(w, d, weff);
    rowptr_kernel<<<(E + 255) / 256, 256, 0, stream>>>(rows, rp, E, N);

    int nblocks = (N + 3) / 4;
    fused_kernel<<<nblocks, 256, 0, stream>>>(x, x0, vals, alpha, cols, rp, weff,
                                              (float*)d_out, N);
}

// Round 3
// 187.686 us; speedup vs baseline: 5.9687x; 1.3961x over previous
//
#include <hip/hip_runtime.h>
#include <math.h>

#define FEAT 128
#define RPB 16  // rows per block in the fused kernel

// ---------------- bf16 helpers (manual RNE; inputs are finite normals) -----
__device__ __forceinline__ unsigned short f2bf(float f) {
    union { float f; unsigned u; } v; v.f = f;
    unsigned r = v.u + 0x7fffu + ((v.u >> 16) & 1u);
    return (unsigned short)(r >> 16);
}
__device__ __forceinline__ float bf_lo(unsigned u) {
    union { unsigned u; float f; } v; v.u = u << 16; return v.f;
}
__device__ __forceinline__ float bf_hi(unsigned u) {
    union { unsigned u; float f; } v; v.u = u & 0xffff0000u; return v.f;
}

// ---------------------------------------------------------------------------
// Kernel 0: convert x (f32) -> xh (packed bf16), 8 elements / thread.
// ---------------------------------------------------------------------------
__global__ __launch_bounds__(256) void cvt_kernel(const float* __restrict__ x,
                                                  uint4* __restrict__ xh,
                                                  int nthreads_total) {
    int t = blockIdx.x * 256 + threadIdx.x;
    if (t >= nthreads_total) return;
    const float4* xp = reinterpret_cast<const float4*>(x) + (size_t)t * 2;
    float4 a = xp[0], b = xp[1];
    uint4 o;
    o.x = (unsigned)f2bf(a.x) | ((unsigned)f2bf(a.y) << 16);
    o.y = (unsigned)f2bf(a.z) | ((unsigned)f2bf(a.w) << 16);
    o.z = (unsigned)f2bf(b.x) | ((unsigned)f2bf(b.y) << 16);
    o.w = (unsigned)f2bf(b.z) | ((unsigned)f2bf(b.w) << 16);
    xh[t] = o;
}

// ---------------------------------------------------------------------------
// Kernel 1: w_eff[i][k] = sum_j w[i][j]*clip(d[j],0,1)*w[k][j]
// ---------------------------------------------------------------------------
__global__ __launch_bounds__(FEAT) void weff_kernel(const float* __restrict__ w,
                                                    const float* __restrict__ d,
                                                    float* __restrict__ weff) {
    __shared__ float wT[FEAT * FEAT];
    __shared__ float as[FEAT];
    const int i = blockIdx.x;
    const int k = threadIdx.x;

    for (int j = 0; j < FEAT; j += 4) {
        float4 v = *reinterpret_cast<const float4*>(&w[k * FEAT + j]);
        wT[(j + 0) * FEAT + k] = v.x;
        wT[(j + 1) * FEAT + k] = v.y;
        wT[(j + 2) * FEAT + k] = v.z;
        wT[(j + 3) * FEAT + k] = v.w;
    }
    float dk = d[k];
    dk = fminf(fmaxf(dk, 0.0f), 1.0f);
    as[k] = w[i * FEAT + k] * dk;
    __syncthreads();

    float acc = 0.0f;
#pragma unroll 8
    for (int j = 0; j < FEAT; ++j)
        acc = fmaf(as[j], wT[j * FEAT + k], acc);
    weff[i * FEAT + k] = acc;
}

// ---------------------------------------------------------------------------
// Kernel 2: build CSR row_ptr from sorted adj_rows.
// ---------------------------------------------------------------------------
__global__ void rowptr_kernel(const int* __restrict__ rows, int* __restrict__ rp,
                              int E, int N) {
    int e = blockIdx.x * blockDim.x + threadIdx.x;
    if (e >= E) return;
    int r = rows[e];
    int rprev = (e == 0) ? -1 : rows[e - 1];
    for (int rr = rprev + 1; rr <= r; ++rr) rp[rr] = e;
    if (e == E - 1) {
        for (int rr = r + 1; rr <= N; ++rr) rp[rr] = E;
    }
}

// ---------------------------------------------------------------------------
// Kernel 3: fused SpMM + x@w_eff + combine. 16 rows/block, 4 waves.
// Phase A: wave-per-row gather, scalar (readfirstlane) cols/vals, uniform-base
//   row loads (bf16: 256 B row = 1 dword/lane; f32: 512 B row = float2/lane).
// Phase B: block-cooperative dense xw = x@w_eff, 8 rows/thread weff reuse.
// ---------------------------------------------------------------------------
template <bool BF16>
__global__ __launch_bounds__(256, 8) void fused_kernel(
    const float* __restrict__ x, const unsigned* __restrict__ xh,
    const float* __restrict__ x0, const float* __restrict__ vals,
    const float* __restrict__ alpha, const int* __restrict__ cols,
    const int* __restrict__ rp, const float* __restrict__ weff,
    float* __restrict__ out, int N) {
    __shared__ float xs[RPB][FEAT];   // 8 KB
    __shared__ float axs[RPB][FEAT];  // 8 KB

    const int tid = threadIdx.x;
    const int lane = tid & 63;
    const int wid = tid >> 6;
    const int rbase = blockIdx.x * RPB;

    // ---- stage the block's x rows into LDS as f32 ----
    if (BF16) {
#pragma unroll
        for (int t = 0; t < 4; ++t) {
            int idx = t * 256 + tid;  // dword index over 16 rows * 64 dwords
            int row = idx >> 6, off = idx & 63;
            if (rbase + row < N) {
                unsigned u = xh[(size_t)(rbase + row) * 64 + off];
                xs[row][off * 2 + 0] = bf_lo(u);
                xs[row][off * 2 + 1] = bf_hi(u);
            }
        }
    } else {
#pragma unroll
        for (int t = 0; t < 8; ++t) {
            int idx = t * 256 + tid;  // float index over 16 rows * 128
            int row = idx >> 7, off = idx & 127;
            if (rbase + row < N) xs[row][off] = x[(size_t)(rbase + row) * FEAT + off];
        }
    }

    // ---- Phase A: gather. Wave w owns rows rbase + w*4 .. w*4+3 ----
    for (int i = 0; i < 4; ++i) {
        const int r = rbase + wid * 4 + i;
        if (r >= N) break;
        const int e0 = __builtin_amdgcn_readfirstlane(rp[r]);
        const int e1 = __builtin_amdgcn_readfirstlane(rp[r + 1]);
        float ax0 = 0.f, ax1 = 0.f;
        int e = e0;
        for (; e + 8 <= e1; e += 8) {
            int c[8];
            float v[8];
#pragma unroll
            for (int k = 0; k < 8; ++k) {
                c[k] = __builtin_amdgcn_readfirstlane(cols[e + k]);
                v[k] = __uint_as_float(
                    __builtin_amdgcn_readfirstlane(__float_as_uint(vals[e + k])));
            }
            if (BF16) {
                unsigned g[8];
#pragma unroll
                for (int k = 0; k < 8; ++k) g[k] = xh[(size_t)c[k] * 64 + lane];
#pragma unroll
                for (int k = 0; k < 8; ++k) {
                    ax0 = fmaf(v[k], bf_lo(g[k]), ax0);
                    ax1 = fmaf(v[k], bf_hi(g[k]), ax1);
                }
            } else {
                float2 g[8];
#pragma unroll
                for (int k = 0; k < 8; ++k)
                    g[k] = *reinterpret_cast<const float2*>(
                        &x[(size_t)c[k] * FEAT + lane * 2]);
#pragma unroll
                for (int k = 0; k < 8; ++k) {
                    ax0 = fmaf(v[k], g[k].x, ax0);
                    ax1 = fmaf(v[k], g[k].y, ax1);
                }
            }
        }
        for (; e < e1; ++e) {
            int c = __builtin_amdgcn_readfirstlane(cols[e]);
            float v = __uint_as_float(
                __builtin_amdgcn_readfirstlane(__float_as_uint(vals[e])));
            if (BF16) {
                unsigned g = xh[(size_t)c * 64 + lane];
                ax0 = fmaf(v, bf_lo(g), ax0);
                ax1 = fmaf(v, bf_hi(g), ax1);
            } else {
                float2 g = *reinterpret_cast<const float2*>(
                    &x[(size_t)c * FEAT + lane * 2]);
                ax0 = fmaf(v, g.x, ax0);
                ax1 = fmaf(v, g.y, ax1);
            }
        }
        axs[wid * 4 + i][lane * 2 + 0] = ax0;
        axs[wid * 4 + i][lane * 2 + 1] = ax1;
    }
    __syncthreads();

    // ---- Phase B: dense xw = xs @ weff, 8 rows per thread ----
    const int f = tid & 127;
    const int g8 = (tid >> 7) * 8;  // first row of my group
    float xw[8] = {0.f, 0.f, 0.f, 0.f, 0.f, 0.f, 0.f, 0.f};
    for (int j = 0; j < FEAT; j += 2) {
        float w0 = weff[(j + 0) * FEAT + f];
        float w1 = weff[(j + 1) * FEAT + f];
#pragma unroll
        for (int i = 0; i < 8; ++i) {
            xw[i] = fmaf(xs[g8 + i][j + 0], w0, xw[i]);
            xw[i] = fmaf(xs[g8 + i][j + 1], w1, xw[i]);
        }
    }

    // ---- epilogue ----
#pragma unroll
    for (int i = 0; i < 8; ++i) {
        int r = rbase + g8 + i;
        if (r < N) {
            float al = 1.0f / (1.0f + __expf(-alpha[r]));
            float xv = xs[g8 + i][f];
            float o = al * 0.5f * (axs[g8 + i][f] - xv) + xw[i] - xv +
                      x0[(size_t)r * FEAT + f];
            out[(size_t)r * FEAT + f] = o;
        }
    }
}

// ---------------------------------------------------------------------------
extern "C" void kernel_launch(void* const* d_in, const int* in_sizes, int n_in,
                              void* d_out, int out_size, void* d_ws, size_t ws_size,
                              hipStream_t stream) {
    const float* x     = (const float*)d_in[0];
    const float* x0    = (const float*)d_in[1];
    const float* vals  = (const float*)d_in[2];
    const float* alpha = (const float*)d_in[3];
    const float* w     = (const float*)d_in[4];
    const float* d     = (const float*)d_in[5];
    const int*   rows  = (const int*)d_in[6];
    const int*   cols  = (const int*)d_in[7];

    const int N = in_sizes[3];
    const int E = in_sizes[2];

    const size_t rp_off = 64 * 1024;                                   // after weff
    const size_t xh_off = (rp_off + (size_t)(N + 1) * 4 + 255) & ~255ULL;
    const size_t need = xh_off + (size_t)N * FEAT * 2;

    float*    weff = (float*)d_ws;
    int*      rp   = (int*)((char*)d_ws + rp_off);
    unsigned* xh   = (unsigned*)((char*)d_ws + xh_off);
    const bool use_bf16 = (ws_size >= need);

    weff_kernel<<<FEAT, FEAT, 0, stream>>>(w, d, weff);
    rowptr_kernel<<<(E + 255) / 256, 256, 0, stream>>>(rows, rp, E, N);

    const int nblocks = (N + RPB - 1) / RPB;
    if (use_bf16) {
        int nt = (N * FEAT) / 8;  // 8 elements per thread
        cvt_kernel<<<(nt + 255) / 256, 256, 0, stream>>>(x, (uint4*)xh, nt);
        fused_kernel<true><<<nblocks, 256, 0, stream>>>(
            x, xh, x0, vals, alpha, cols, rp, weff, (float*)d_out, N);
    } else {
        fused_kernel<false><<<nblocks, 256, 0, stream>>>(
            x, xh, x0, vals, alpha, cols, rp, weff, (float*)d_out, N);
    }
}

// Round 4
// 182.752 us; speedup vs baseline: 6.1298x; 1.0270x over previous
//
#include <hip/hip_runtime.h>
#include <math.h>

#define FEAT 128
#define RPB 16  // rows per block in the fused kernel

// ---------------- bf16 helpers (manual RNE; inputs are finite normals) -----
__device__ __forceinline__ unsigned short f2bf(float f) {
    union { float f; unsigned u; } v; v.f = f;
    unsigned r = v.u + 0x7fffu + ((v.u >> 16) & 1u);
    return (unsigned short)(r >> 16);
}
__device__ __forceinline__ float bf_lo(unsigned u) {
    union { unsigned u; float f; } v; v.u = u << 16; return v.f;
}
__device__ __forceinline__ float bf_hi(unsigned u) {
    union { unsigned u; float f; } v; v.u = u & 0xffff0000u; return v.f;
}

// ---------------------------------------------------------------------------
// Kernel 0: convert x (f32) -> xh (packed bf16), 8 elements / thread.
// ---------------------------------------------------------------------------
__global__ __launch_bounds__(256) void cvt_kernel(const float* __restrict__ x,
                                                  uint4* __restrict__ xh,
                                                  int nthreads_total) {
    int t = blockIdx.x * 256 + threadIdx.x;
    if (t >= nthreads_total) return;
    const float4* xp = reinterpret_cast<const float4*>(x) + (size_t)t * 2;
    float4 a = xp[0], b = xp[1];
    uint4 o;
    o.x = (unsigned)f2bf(a.x) | ((unsigned)f2bf(a.y) << 16);
    o.y = (unsigned)f2bf(a.z) | ((unsigned)f2bf(a.w) << 16);
    o.z = (unsigned)f2bf(b.x) | ((unsigned)f2bf(b.y) << 16);
    o.w = (unsigned)f2bf(b.z) | ((unsigned)f2bf(b.w) << 16);
    xh[t] = o;
}

// ---------------------------------------------------------------------------
// Kernel 1: w_eff[i][k] = sum_j w[i][j]*clip(d[j],0,1)*w[k][j]
// ---------------------------------------------------------------------------
__global__ __launch_bounds__(FEAT) void weff_kernel(const float* __restrict__ w,
                                                    const float* __restrict__ d,
                                                    float* __restrict__ weff) {
    __shared__ float wT[FEAT * FEAT];
    __shared__ float as[FEAT];
    const int i = blockIdx.x;
    const int k = threadIdx.x;

    for (int j = 0; j < FEAT; j += 4) {
        float4 v = *reinterpret_cast<const float4*>(&w[k * FEAT + j]);
        wT[(j + 0) * FEAT + k] = v.x;
        wT[(j + 1) * FEAT + k] = v.y;
        wT[(j + 2) * FEAT + k] = v.z;
        wT[(j + 3) * FEAT + k] = v.w;
    }
    float dk = d[k];
    dk = fminf(fmaxf(dk, 0.0f), 1.0f);
    as[k] = w[i * FEAT + k] * dk;
    __syncthreads();

    float acc = 0.0f;
#pragma unroll 8
    for (int j = 0; j < FEAT; ++j)
        acc = fmaf(as[j], wT[j * FEAT + k], acc);
    weff[i * FEAT + k] = acc;
}

// ---------------------------------------------------------------------------
// Kernel 2: build CSR row_ptr from sorted adj_rows.
// ---------------------------------------------------------------------------
__global__ void rowptr_kernel(const int* __restrict__ rows, int* __restrict__ rp,
                              int E, int N) {
    int e = blockIdx.x * blockDim.x + threadIdx.x;
    if (e >= E) return;
    int r = rows[e];
    int rprev = (e == 0) ? -1 : rows[e - 1];
    for (int rr = rprev + 1; rr <= r; ++rr) rp[rr] = e;
    if (e == E - 1) {
        for (int rr = r + 1; rr <= N; ++rr) rp[rr] = E;
    }
}

// ---------------------------------------------------------------------------
// Kernel 3: fused SpMM + x@w_eff + combine. 16 rows/block, 4 waves.
// Phase A (bf16): 4 edges per global_load_dwordx4 (1 KB/instr). Lane =
//   (grp = lane>>4 -> edge slot, fl = lane&15 -> 16B chunk = features
//   fl*8..fl*8+7). Metadata (cols/vals) via uniform-index scalar loads.
//   Per-lane acc over fixed features; shfl_xor(16/32) reduce per row.
// Phase B: block-cooperative dense xw = x@w_eff, 8 rows/thread weff reuse.
// ---------------------------------------------------------------------------
template <bool BF16>
__global__ __launch_bounds__(256, 8) void fused_kernel(
    const float* __restrict__ x, const unsigned* __restrict__ xh,
    const float* __restrict__ x0, const float* __restrict__ vals,
    const float* __restrict__ alpha, const int* __restrict__ cols,
    const int* __restrict__ rp, const float* __restrict__ weff,
    float* __restrict__ out, int N) {
    __shared__ float xs[RPB][FEAT];   // 8 KB
    __shared__ float axs[RPB][FEAT];  // 8 KB

    const int tid = threadIdx.x;
    const int lane = tid & 63;
    const int wid = tid >> 6;
    const int rbase = blockIdx.x * RPB;

    // ---- stage the block's x rows into LDS as f32 ----
    if (BF16) {
#pragma unroll
        for (int t = 0; t < 4; ++t) {
            int idx = t * 256 + tid;  // dword index over 16 rows * 64 dwords
            int row = idx >> 6, off = idx & 63;
            if (rbase + row < N) {
                unsigned u = xh[(size_t)(rbase + row) * 64 + off];
                xs[row][off * 2 + 0] = bf_lo(u);
                xs[row][off * 2 + 1] = bf_hi(u);
            }
        }
    } else {
#pragma unroll
        for (int t = 0; t < 8; ++t) {
            int idx = t * 256 + tid;  // float index over 16 rows * 128
            int row = idx >> 7, off = idx & 127;
            if (rbase + row < N) xs[row][off] = x[(size_t)(rbase + row) * FEAT + off];
        }
    }

    // ---- Phase A ----
    if (BF16) {
        const int grp = lane >> 4;   // edge slot 0..3
        const int fl = lane & 15;    // 16B chunk (features fl*8 .. fl*8+7)
        const bool sel1 = (grp & 1) != 0;
        const bool sel2 = (grp & 2) != 0;

        for (int i = 0; i < 4; ++i) {
            const int r = rbase + wid * 4 + i;
            if (r >= N) break;
            const int e0 = __builtin_amdgcn_readfirstlane(rp[r]);
            const int e1 = __builtin_amdgcn_readfirstlane(rp[r + 1]);
            float acc[8] = {0.f, 0.f, 0.f, 0.f, 0.f, 0.f, 0.f, 0.f};
            int e = e0;
            // main: 8 edges / iter, two dwordx4 gathers in flight
            for (; e + 8 <= e1; e += 8) {
                int c[8];
                float v[8];
#pragma unroll
                for (int k = 0; k < 8; ++k) {
                    c[k] = cols[e + k];   // uniform index -> s_load
                    v[k] = vals[e + k];
                }
                int colA = sel2 ? (sel1 ? c[3] : c[2]) : (sel1 ? c[1] : c[0]);
                int colB = sel2 ? (sel1 ? c[7] : c[6]) : (sel1 ? c[5] : c[4]);
                float vA = sel2 ? (sel1 ? v[3] : v[2]) : (sel1 ? v[1] : v[0]);
                float vB = sel2 ? (sel1 ? v[7] : v[6]) : (sel1 ? v[5] : v[4]);
                uint4 gA = *reinterpret_cast<const uint4*>(
                    &xh[(size_t)colA * 64 + fl * 4]);
                uint4 gB = *reinterpret_cast<const uint4*>(
                    &xh[(size_t)colB * 64 + fl * 4]);
                acc[0] = fmaf(vA, bf_lo(gA.x), acc[0]);
                acc[1] = fmaf(vA, bf_hi(gA.x), acc[1]);
                acc[2] = fmaf(vA, bf_lo(gA.y), acc[2]);
                acc[3] = fmaf(vA, bf_hi(gA.y), acc[3]);
                acc[4] = fmaf(vA, bf_lo(gA.z), acc[4]);
                acc[5] = fmaf(vA, bf_hi(gA.z), acc[5]);
                acc[6] = fmaf(vA, bf_lo(gA.w), acc[6]);
                acc[7] = fmaf(vA, bf_hi(gA.w), acc[7]);
                acc[0] = fmaf(vB, bf_lo(gB.x), acc[0]);
                acc[1] = fmaf(vB, bf_hi(gB.x), acc[1]);
                acc[2] = fmaf(vB, bf_lo(gB.y), acc[2]);
                acc[3] = fmaf(vB, bf_hi(gB.y), acc[3]);
                acc[4] = fmaf(vB, bf_lo(gB.z), acc[4]);
                acc[5] = fmaf(vB, bf_hi(gB.z), acc[5]);
                acc[6] = fmaf(vB, bf_lo(gB.w), acc[6]);
                acc[7] = fmaf(vB, bf_hi(gB.w), acc[7]);
            }
            // tail: 4 edges / iter, masked
            for (; e < e1; e += 4) {
                int c[4];
                float v[4];
#pragma unroll
                for (int k = 0; k < 4; ++k) {
                    int ek = (e + k < e1) ? (e + k) : e0;  // e0 always valid here
                    c[k] = cols[ek];
                    v[k] = (e + k < e1) ? vals[ek] : 0.0f;
                }
                int colA = sel2 ? (sel1 ? c[3] : c[2]) : (sel1 ? c[1] : c[0]);
                float vA = sel2 ? (sel1 ? v[3] : v[2]) : (sel1 ? v[1] : v[0]);
                uint4 gA = *reinterpret_cast<const uint4*>(
                    &xh[(size_t)colA * 64 + fl * 4]);
                acc[0] = fmaf(vA, bf_lo(gA.x), acc[0]);
                acc[1] = fmaf(vA, bf_hi(gA.x), acc[1]);
                acc[2] = fmaf(vA, bf_lo(gA.y), acc[2]);
                acc[3] = fmaf(vA, bf_hi(gA.y), acc[3]);
                acc[4] = fmaf(vA, bf_lo(gA.z), acc[4]);
                acc[5] = fmaf(vA, bf_hi(gA.z), acc[5]);
                acc[6] = fmaf(vA, bf_lo(gA.w), acc[6]);
                acc[7] = fmaf(vA, bf_hi(gA.w), acc[7]);
            }
            // reduce the 4 edge-slot partials (lanes differ only in grp)
#pragma unroll
            for (int k = 0; k < 8; ++k) {
                acc[k] += __shfl_xor(acc[k], 16);
                acc[k] += __shfl_xor(acc[k], 32);
            }
            if (grp == 0) {
                float4 o0 = make_float4(acc[0], acc[1], acc[2], acc[3]);
                float4 o1 = make_float4(acc[4], acc[5], acc[6], acc[7]);
                *reinterpret_cast<float4*>(&axs[wid * 4 + i][fl * 8 + 0]) = o0;
                *reinterpret_cast<float4*>(&axs[wid * 4 + i][fl * 8 + 4]) = o1;
            }
        }
    } else {
        // f32 fallback: per-edge float2 gather (round-3 path)
        for (int i = 0; i < 4; ++i) {
            const int r = rbase + wid * 4 + i;
            if (r >= N) break;
            const int e0 = __builtin_amdgcn_readfirstlane(rp[r]);
            const int e1 = __builtin_amdgcn_readfirstlane(rp[r + 1]);
            float ax0 = 0.f, ax1 = 0.f;
            for (int e = e0; e < e1; ++e) {
                int c = cols[e];
                float v = vals[e];
                float2 g = *reinterpret_cast<const float2*>(
                    &x[(size_t)c * FEAT + lane * 2]);
                ax0 = fmaf(v, g.x, ax0);
                ax1 = fmaf(v, g.y, ax1);
            }
            axs[wid * 4 + i][lane * 2 + 0] = ax0;
            axs[wid * 4 + i][lane * 2 + 1] = ax1;
        }
    }
    __syncthreads();

    // ---- Phase B: dense xw = xs @ weff, 8 rows per thread ----
    const int f = tid & 127;
    const int g8 = (tid >> 7) * 8;  // first row of my group
    float xw[8] = {0.f, 0.f, 0.f, 0.f, 0.f, 0.f, 0.f, 0.f};
    for (int j = 0; j < FEAT; j += 2) {
        float w0 = weff[(j + 0) * FEAT + f];
        float w1 = weff[(j + 1) * FEAT + f];
#pragma unroll
        for (int i = 0; i < 8; ++i) {
            xw[i] = fmaf(xs[g8 + i][j + 0], w0, xw[i]);
            xw[i] = fmaf(xs[g8 + i][j + 1], w1, xw[i]);
        }
    }

    // ---- epilogue ----
#pragma unroll
    for (int i = 0; i < 8; ++i) {
        int r = rbase + g8 + i;
        if (r < N) {
            float al = 1.0f / (1.0f + __expf(-alpha[r]));
            float xv = xs[g8 + i][f];
            float o = al * 0.5f * (axs[g8 + i][f] - xv) + xw[i] - xv +
                      x0[(size_t)r * FEAT + f];
            out[(size_t)r * FEAT + f] = o;
        }
    }
}

// ---------------------------------------------------------------------------
extern "C" void kernel_launch(void* const* d_in, const int* in_sizes, int n_in,
                              void* d_out, int out_size, void* d_ws, size_t ws_size,
                              hipStream_t stream) {
    const float* x     = (const float*)d_in[0];
    const float* x0    = (const float*)d_in[1];
    const float* vals  = (const float*)d_in[2];
    const float* alpha = (const float*)d_in[3];
    const float* w     = (const float*)d_in[4];
    const float* d     = (const float*)d_in[5];
    const int*   rows  = (const int*)d_in[6];
    const int*   cols  = (const int*)d_in[7];

    const int N = in_sizes[3];
    const int E = in_sizes[2];

    const size_t rp_off = 64 * 1024;  // after weff
    const size_t xh_off = (rp_off + (size_t)(N + 1) * 4 + 255) & ~255ULL;
    const size_t need = xh_off + (size_t)N * FEAT * 2;

    float*    weff = (float*)d_ws;
    int*      rp   = (int*)((char*)d_ws + rp_off);
    unsigned* xh   = (unsigned*)((char*)d_ws + xh_off);
    const bool use_bf16 = (ws_size >= need);

    weff_kernel<<<FEAT, FEAT, 0, stream>>>(w, d, weff);
    rowptr_kernel<<<(E + 255) / 256, 256, 0, stream>>>(rows, rp, E, N);

    const int nblocks = (N + RPB - 1) / RPB;
    if (use_bf16) {
        int nt = (N * FEAT) / 8;  // 8 elements per thread
        cvt_kernel<<<(nt + 255) / 256, 256, 0, stream>>>(x, (uint4*)xh, nt);
        fused_kernel<true><<<nblocks, 256, 0, stream>>>(
            x, xh, x0, vals, alpha, cols, rp, weff, (float*)d_out, N);
    } else {
        fused_kernel<false><<<nblocks, 256, 0, stream>>>(
            x, xh, x0, vals, alpha, cols, rp, weff, (float*)d_out, N);
    }
}